// Round 4
// baseline (180.316 us; speedup 1.0000x reference)
//
#include <hip/hip_runtime.h>
#include <math.h>

// Monotone cubic spline flow (neural spline flow, cubic variant).
// B*D = 2,097,152 elements, K = 8 bins.
// R4: persistent grid-stride waves + register double-buffered software
// pipeline. Loads for element j+stride are issued BEFORE the ~1200-cycle
// compute of element j, so each wave hides memory latency itself instead of
// burst-load-then-stall at wave start (R1-R3 all pinned at ~63us with idle
// VALU -- scheduling theory). NT stores: outputs are write-once streams.

constexpr int K = 8;
constexpr float TAIL = 3.0f;
constexpr float MIN_BIN = 0.001f;
constexpr float SEARCH_EPS = 1e-6f;

__device__ __forceinline__ float rcpf(float v) {
    return __builtin_amdgcn_rcpf(v);   // v_rcp_f32, ~1 ulp
}

__global__ __launch_bounds__(256) void cbs_kernel(
    const float* __restrict__ x_,
    const float* __restrict__ w_,
    const float* __restrict__ h_,
    const float* __restrict__ dl_,
    const float* __restrict__ dr_,
    float* __restrict__ out,
    float* __restrict__ lad,
    int n)
{
    const int tid    = blockIdx.x * blockDim.x + threadIdx.x;
    const int stride = gridDim.x * blockDim.x;

    // ---- prefetch registers (next element) ----
    float4 nwa, nwb, nha, nhb;
    float  nx, ndl, ndr;

    int j = tid;
    if (j < n) {
        const float4* w4 = (const float4*)w_ + 2 * (size_t)j;
        const float4* h4 = (const float4*)h_ + 2 * (size_t)j;
        nwa = w4[0]; nwb = w4[1];
        nha = h4[0]; nhb = h4[1];
        nx  = x_[j]; ndl = dl_[j]; ndr = dr_[j];
    }

    while (j < n) {
        // rotate prefetch -> current
        const float4 wa = nwa, wb = nwb, ha = nha, hb = nhb;
        const float  xv = nx, dlv = ndl, drv = ndr;
        const int cur = j;
        j += stride;

        // issue next element's loads NOW; waitcnt lands at next loop top
        if (j < n) {
            const float4* w4 = (const float4*)w_ + 2 * (size_t)j;
            const float4* h4 = (const float4*)h_ + 2 * (size_t)j;
            nwa = w4[0]; nwb = w4[1];
            nha = h4[0]; nhb = h4[1];
            nx  = x_[j]; ndl = dl_[j]; ndr = dr_[j];
        }

        float wr[K] = {wa.x, wa.y, wa.z, wa.w, wb.x, wb.y, wb.z, wb.w};
        float hr[K] = {ha.x, ha.y, ha.z, ha.w, hb.x, hb.y, hb.z, hb.w};

        // softmax + min-bin affine (no max-subtract: inputs ~N(0,1), fp32 safe)
        float sw = 0.0f;
        #pragma unroll
        for (int k = 0; k < K; k++) { wr[k] = __expf(wr[k]); sw += wr[k]; }
        float cs = (1.0f - MIN_BIN * K) * rcpf(sw);
        #pragma unroll
        for (int k = 0; k < K; k++) wr[k] = MIN_BIN + cs * wr[k];

        float sh = 0.0f;
        #pragma unroll
        for (int k = 0; k < K; k++) { hr[k] = __expf(hr[k]); sh += hr[k]; }
        float csh = (1.0f - MIN_BIN * K) * rcpf(sh);
        #pragma unroll
        for (int k = 0; k < K; k++) hr[k] = MIN_BIN + csh * hr[k];

        // cumulative knots
        float cw[K + 1]; cw[0] = 0.0f;
        #pragma unroll
        for (int k = 0; k < K; k++) cw[k + 1] = cw[k] + wr[k];
        float ch[K + 1]; ch[0] = 0.0f;
        #pragma unroll
        for (int k = 0; k < K; k++) ch[k + 1] = ch[k] + hr[k];

        // slopes (all > 0 since widths/heights >= MIN_BIN)
        float s[K];
        #pragma unroll
        for (int k = 0; k < K; k++) s[k] = hr[k] * rcpf(wr[k]);

        // knot derivatives; interior = min(2*min(s_k,s_k+1), 2*m2), signs fold
        float dv[K + 1];
        dv[0] = rcpf(1.0f + __expf(-dlv)) * 3.0f * s[0];
        dv[K] = rcpf(1.0f + __expf(-drv)) * 3.0f * s[K - 1];
        #pragma unroll
        for (int k = 0; k < K - 1; k++) {
            float two_m1 = 2.0f * fminf(s[k], s[k + 1]);
            float m2x = (wr[k + 1] * s[k] + wr[k] * s[k + 1])
                        * rcpf(wr[k] + wr[k + 1]);   // == 2 * m2
            dv[k + 1] = fminf(two_m1, m2x);
        }

        // normalized position & bin search
        float t = (xv + TAIL) * (1.0f / (2.0f * TAIL));
        t = fminf(fmaxf(t, 0.0f), 1.0f);

        int bin = 0;
        #pragma unroll
        for (int jj = 1; jj < K; jj++) bin += (t >= cw[jj]) ? 1 : 0;
        bin += (t >= 1.0f + SEARCH_EPS) ? 1 : 0;   // last knot = 1 + eps
        if (bin > K - 1) bin = K - 1;

        // gather per-bin quantities
        float wk = wr[0], sk = s[0], d0 = dv[0], d1 = dv[1], lw = cw[0], dd = ch[0];
        #pragma unroll
        for (int k = 1; k < K; k++) {
            bool sel = (bin == k);
            wk = sel ? wr[k]     : wk;
            sk = sel ? s[k]      : sk;
            d0 = sel ? dv[k]     : d0;
            d1 = sel ? dv[k + 1] : d1;
            lw = sel ? cw[k]     : lw;
            dd = sel ? ch[k]     : dd;
        }

        float inv_wk = rcpf(wk);
        float ia = (d0 + d1 - 2.0f * sk) * inv_wk * inv_wk;
        float ib = (3.0f * sk - 2.0f * d0 - d1) * inv_wk;
        float ic = d0;

        float sx = t - lw;
        float out_s = ((ia * sx + ib) * sx + ic) * sx + dd;
        float der   = (3.0f * ia * sx + 2.0f * ib) * sx + ic;
        float lad_s = __logf(fabsf(der));   // + log(6) - log(6) == 0

        out_s = fminf(fmaxf(out_s, 0.0f), 1.0f) * (2.0f * TAIL) - TAIL;

        bool inside = (xv >= -TAIL) && (xv <= TAIL);
        __builtin_nontemporal_store(inside ? out_s : xv,   out + cur);
        __builtin_nontemporal_store(inside ? lad_s : 0.0f, lad + cur);
    }
}

extern "C" void kernel_launch(void* const* d_in, const int* in_sizes, int n_in,
                              void* d_out, int out_size, void* d_ws, size_t ws_size,
                              hipStream_t stream) {
    const float* x  = (const float*)d_in[0];
    const float* w  = (const float*)d_in[1];
    const float* h  = (const float*)d_in[2];
    const float* dl = (const float*)d_in[3];
    const float* dr = (const float*)d_in[4];
    int n = in_sizes[0];               // 8192*256 = 2,097,152
    float* out = (float*)d_out;        // outputs, then logabsdet, concatenated
    float* lad = out + n;

    const int threads = 256;
    const int blocks  = 2048;          // 256 CUs x 8 blocks; 4 elements/thread
    cbs_kernel<<<blocks, threads, 0, stream>>>(x, w, h, dl, dr, out, lad, n);
}